// Round 10
// baseline (325.222 us; speedup 1.0000x reference)
//
#include <hip/hip_runtime.h>

#define D 64
#define BSHIFT 7              // 128 nodes per bucket
#define BNODES (1 << BSHIFT)
#define NBK_MAX 1024          // supports N up to 131072 at BSHIFT=7

typedef __attribute__((ext_vector_type(8))) short bf16x8;
typedef __attribute__((ext_vector_type(4))) float f32x4;

// ---------- bf16 helpers (bit-exact RNE pack, shift-based unpack) ----------
__device__ __forceinline__ unsigned int f2bf_rne(float f) {
    unsigned int b = __float_as_uint(f);
    return (b + 0x7fffu + ((b >> 16) & 1u)) >> 16;
}
__device__ __forceinline__ unsigned int pack_bf(float lo, float hi) {
    return f2bf_rne(lo) | (f2bf_rne(hi) << 16);
}
__device__ __forceinline__ float bflo(unsigned int u) { return __uint_as_float(u << 16); }
__device__ __forceinline__ float bfhi(unsigned int u) { return __uint_as_float(u & 0xffff0000u); }

// ---------- zero int region ----------
__global__ void zeroi_kernel(int* __restrict__ p, int n) {
    int i = blockIdx.x * blockDim.x + threadIdx.x;
    if (i < n) p[i] = 0;
}

// ---------- cast fp32 features -> packed bf16 (2 feats per uint) ----------
__global__ void cast_kernel(const float4* __restrict__ xin, uint2* __restrict__ xb, int n4) {
    int i = blockIdx.x * blockDim.x + threadIdx.x;
    int stride = gridDim.x * blockDim.x;
    for (; i < n4; i += stride) {
        float4 v = xin[i];
        uint2 o;
        o.x = pack_bf(v.x, v.y);
        o.y = pack_bf(v.z, v.w);
        xb[i] = o;
    }
}

// ---------- phase 1: per-(bucket,group) histogram. group = blockIdx&7 (~XCD) ----------
__global__ __launch_bounds__(256) void hist2_kernel(const int* __restrict__ dst,
                                                    int* __restrict__ cnt2,
                                                    int E, int NBK, int CE) {
    __shared__ int lh[NBK_MAX];
    for (int k = threadIdx.x; k < NBK; k += 256) lh[k] = 0;
    __syncthreads();
    int b = blockIdx.x, g = b & 7;
    int beg = b * CE, end = min(beg + CE, E);
    for (int e = beg + threadIdx.x; e < end; e += 256)
        atomicAdd(&lh[dst[e] >> BSHIFT], 1);
    __syncthreads();
    for (int k = threadIdx.x; k < NBK; k += 256)
        if (lh[k]) atomicAdd(&cnt2[(k << 3) | g], lh[k]);
}

// ---------- phase 2: exclusive scan of cnt2[NBK*8] -> cur2 + bstart (chunked, NBK<=1024) ----------
__global__ __launch_bounds__(256) void scan2k_kernel(const int* __restrict__ cnt2,
                                                     int* __restrict__ cur2,
                                                     int* __restrict__ bstart, int NBK) {
    __shared__ int s[256];
    int n = NBK << 3;
    int per = (n + 255) / 256;        // <= 32
    int tid = threadIdx.x;
    int base = tid * per;
    int loc[32];
    int sum = 0;
    for (int j = 0; j < per; ++j) {
        int idx = base + j;
        int v = (idx < n) ? cnt2[idx] : 0;
        loc[j] = sum;                 // exclusive within thread
        sum += v;
    }
    s[tid] = sum;
    __syncthreads();
    for (int off = 1; off < 256; off <<= 1) {
        int t = (tid >= off) ? s[tid - off] : 0;
        __syncthreads();
        s[tid] += t;
        __syncthreads();
    }
    int ebase = s[tid] - sum;
    for (int j = 0; j < per; ++j) {
        int idx = base + j;
        if (idx < n) {
            int e = ebase + loc[j];
            cur2[idx] = e;
            if ((idx & 7) == 0) bstart[idx >> 3] = e;   // bucket start
        }
    }
    if (tid == 0) bstart[NBK] = s[255];  // == E
}

// ---------- phase 3: scatter packed (src | dst_low<<17) records ----------
__global__ __launch_bounds__(256) void binscatter_kernel(
    const int* __restrict__ src, const int* __restrict__ dst,
    int* __restrict__ cur2, unsigned int* __restrict__ pairs,
    int E, int NBK, int CE) {
    __shared__ int lh[NBK_MAX];
    __shared__ int lbase[NBK_MAX];
    for (int k = threadIdx.x; k < NBK; k += 256) lh[k] = 0;
    __syncthreads();
    int b = blockIdx.x, g = b & 7;
    int beg = b * CE, end = min(beg + CE, E);
    for (int e = beg + threadIdx.x; e < end; e += 256)
        atomicAdd(&lh[dst[e] >> BSHIFT], 1);
    __syncthreads();
    for (int k = threadIdx.x; k < NBK; k += 256) {
        int c = lh[k];
        if (c) lbase[k] = atomicAdd(&cur2[(k << 3) | g], c);
        lh[k] = 0;
    }
    __syncthreads();
    for (int e = beg + threadIdx.x; e < end; e += 256) {
        int d = dst[e];
        int k = d >> BSHIFT;
        int r = atomicAdd(&lh[k], 1);
        pairs[lbase[k] + r] = (unsigned int)src[e] | ((unsigned int)(d & (BNODES - 1)) << 17);
    }
}

// ---------- phase 4: one workgroup per bucket -> rowptr + dst-sorted csr ----------
__global__ __launch_bounds__(256) void csr_build_kernel(
    const unsigned int* __restrict__ pairs, const int* __restrict__ bstart,
    int* __restrict__ rowptr, int* __restrict__ csr, int N, int NBK) {
    __shared__ int lcnt[BNODES];
    __shared__ int lofs[BNODES];
    __shared__ int s2[BNODES];
    int k = blockIdx.x;
    int tid = threadIdx.x;
    int node0 = k << BSHIFT;
    int nnodes = min(BNODES, N - node0);
    int rbeg = bstart[k], rend = bstart[k + 1];

    if (tid < BNODES) lcnt[tid] = 0;
    __syncthreads();
    for (int i = rbeg + tid; i < rend; i += 256)
        atomicAdd(&lcnt[pairs[i] >> 17], 1);
    __syncthreads();
    if (tid < BNODES) s2[tid] = lcnt[tid];
    __syncthreads();
    for (int off = 1; off < BNODES; off <<= 1) {
        int t = 0;
        if (tid < BNODES && tid >= off) t = s2[tid - off];
        __syncthreads();
        if (tid < BNODES && tid >= off) s2[tid] += t;
        __syncthreads();
    }
    if (tid < BNODES) lofs[tid] = s2[tid] - lcnt[tid];   // exclusive
    __syncthreads();
    if (tid < nnodes) {
        int p = rbeg + lofs[tid];
        rowptr[node0 + tid] = p;
        lcnt[tid] = p;                 // cursor
    }
    if (k == NBK - 1 && tid == 0) rowptr[N] = rend;
    __syncthreads();
    for (int i = rbeg + tid; i < rend; i += 256) {
        unsigned int rec = pairs[i];
        int j = rec >> 17;
        int pos = atomicAdd(&lcnt[j], 1);
        csr[pos] = (int)(rec & 0x1FFFFu);
    }
}

// ---------- aggregation, bf16: 4 nodes per wave; quarter-wave per node, 8-deep unroll ----------
__global__ __launch_bounds__(256) void agg_bf_kernel(
    const unsigned int* __restrict__ xb, const int* __restrict__ rowptr,
    const int* __restrict__ csr, unsigned int* __restrict__ meanb, int N) {
    int lane = threadIdx.x & 63;
    int q  = lane >> 4;         // which of the wave's 4 nodes
    int fl = lane & 15;         // uint-pair lane
    int wid = blockIdx.x * (blockDim.x >> 6) + (threadIdx.x >> 6);
    int nwaves = gridDim.x * (blockDim.x >> 6);
    int nquads = (N + 3) >> 2;

    for (int p = wid; p < nquads; p += nwaves) {
        int node = p * 4 + q;
        bool valid = node < N;
        int beg = 0, end = 0;
        if (valid) { beg = rowptr[node]; end = rowptr[node + 1]; }
        float s0 = 0.f, s1 = 0.f, s2 = 0.f, s3 = 0.f;
        int j = beg;
        for (; j + 8 <= end; j += 8) {
            int i0 = csr[j],     i1 = csr[j + 1], i2 = csr[j + 2], i3 = csr[j + 3];
            int i4 = csr[j + 4], i5 = csr[j + 5], i6 = csr[j + 6], i7 = csr[j + 7];
            uint2 u0 = *(const uint2*)(xb + i0 * 32 + fl * 2);
            uint2 u1 = *(const uint2*)(xb + i1 * 32 + fl * 2);
            uint2 u2 = *(const uint2*)(xb + i2 * 32 + fl * 2);
            uint2 u3 = *(const uint2*)(xb + i3 * 32 + fl * 2);
            uint2 u4 = *(const uint2*)(xb + i4 * 32 + fl * 2);
            uint2 u5 = *(const uint2*)(xb + i5 * 32 + fl * 2);
            uint2 u6 = *(const uint2*)(xb + i6 * 32 + fl * 2);
            uint2 u7 = *(const uint2*)(xb + i7 * 32 + fl * 2);
            s0 += bflo(u0.x) + bflo(u1.x) + bflo(u2.x) + bflo(u3.x)
                + bflo(u4.x) + bflo(u5.x) + bflo(u6.x) + bflo(u7.x);
            s1 += bfhi(u0.x) + bfhi(u1.x) + bfhi(u2.x) + bfhi(u3.x)
                + bfhi(u4.x) + bfhi(u5.x) + bfhi(u6.x) + bfhi(u7.x);
            s2 += bflo(u0.y) + bflo(u1.y) + bflo(u2.y) + bflo(u3.y)
                + bflo(u4.y) + bflo(u5.y) + bflo(u6.y) + bflo(u7.y);
            s3 += bfhi(u0.y) + bfhi(u1.y) + bfhi(u2.y) + bfhi(u3.y)
                + bfhi(u4.y) + bfhi(u5.y) + bfhi(u6.y) + bfhi(u7.y);
        }
        for (; j + 4 <= end; j += 4) {
            int i0 = csr[j], i1 = csr[j + 1], i2 = csr[j + 2], i3 = csr[j + 3];
            uint2 u0 = *(const uint2*)(xb + i0 * 32 + fl * 2);
            uint2 u1 = *(const uint2*)(xb + i1 * 32 + fl * 2);
            uint2 u2 = *(const uint2*)(xb + i2 * 32 + fl * 2);
            uint2 u3 = *(const uint2*)(xb + i3 * 32 + fl * 2);
            s0 += bflo(u0.x) + bflo(u1.x) + bflo(u2.x) + bflo(u3.x);
            s1 += bfhi(u0.x) + bfhi(u1.x) + bfhi(u2.x) + bfhi(u3.x);
            s2 += bflo(u0.y) + bflo(u1.y) + bflo(u2.y) + bflo(u3.y);
            s3 += bfhi(u0.y) + bfhi(u1.y) + bfhi(u2.y) + bfhi(u3.y);
        }
        for (; j < end; ++j) {
            uint2 u = *(const uint2*)(xb + csr[j] * 32 + fl * 2);
            s0 += bflo(u.x);
            s1 += bfhi(u.x);
            s2 += bflo(u.y);
            s3 += bfhi(u.y);
        }
        if (valid) {
            float inv = 1.0f / fmaxf((float)(end - beg), 1.0f);
            uint2 o;
            o.x = pack_bf(s0 * inv, s1 * inv);
            o.y = pack_bf(s2 * inv, s3 * inv);
            *(uint2*)(meanb + node * 32 + fl * 2) = o;
        }
    }
}

// ---------- linear via MFMA: out[f][node] tiles, D = W * A (no LDS) ----------
__global__ __launch_bounds__(256) void lin_mfma_kernel(
    const unsigned int* __restrict__ meanb, const unsigned int* __restrict__ xin,
    const float* __restrict__ Wl, const float* __restrict__ Wr,
    const float* __restrict__ bias,
    float* __restrict__ outf, unsigned int* __restrict__ outb, int N, int relu) {
    int tid = threadIdx.x;
    int ft   = tid >> 6;        // wave id = f-tile 0..3
    int lane = tid & 63;
    int lm   = lane & 15;
    int quad = lane >> 4;

    // hi/lo split weight frags for the 4 K-steps (W ~ bf16(W) + bf16(W - bf16(W)))
    int f_a = ft * 16 + lm;
    bf16x8 wh[4], wlo[4];
#pragma unroll
    for (int s = 0; s < 4; ++s) {
        int k8 = s * 32 + quad * 8;
        const float* Wsrc = (k8 < 64) ? Wl : Wr;
        const float* p = Wsrc + f_a * 64 + (k8 & 63);
        float4 w0 = *(const float4*)p;
        float4 w1 = *(const float4*)(p + 4);
        float w[8] = {w0.x, w0.y, w0.z, w0.w, w1.x, w1.y, w1.z, w1.w};
        bf16x8 h, l;
#pragma unroll
        for (int j = 0; j < 8; ++j) {
            unsigned int hb = f2bf_rne(w[j]);
            float hf = __uint_as_float(hb << 16);
            unsigned int lb = f2bf_rne(w[j] - hf);
            h[j] = (short)hb;
            l[j] = (short)lb;
        }
        wh[s] = h;
        wlo[s] = l;
    }

    int node0 = blockIdx.x * 64;
    f32x4 acc[4];
#pragma unroll
    for (int nt = 0; nt < 4; ++nt) acc[nt] = (f32x4){0.f, 0.f, 0.f, 0.f};

#pragma unroll
    for (int nt = 0; nt < 4; ++nt) {
        int node = node0 + nt * 16 + lm;
        bool v = node < N;
        const unsigned int* mrow = meanb + (long long)node * 32;
        const unsigned int* xrow = xin   + (long long)node * 32;
#pragma unroll
        for (int s = 0; s < 4; ++s) {
            uint4 u = make_uint4(0u, 0u, 0u, 0u);
            if (v) {
                const unsigned int* srcrow = (s < 2) ? mrow : xrow;
                u = *(const uint4*)(srcrow + (s & 1) * 16 + quad * 4);
            }
            union { uint4 u4; bf16x8 v8; } cv;
            cv.u4 = u;
            acc[nt] = __builtin_amdgcn_mfma_f32_16x16x32_bf16(wh[s],  cv.v8, acc[nt], 0, 0, 0);
            acc[nt] = __builtin_amdgcn_mfma_f32_16x16x32_bf16(wlo[s], cv.v8, acc[nt], 0, 0, 0);
        }
    }

    int fb = ft * 16 + quad * 4;
    float4 bv = *(const float4*)(bias + fb);
#pragma unroll
    for (int nt = 0; nt < 4; ++nt) {
        int node = node0 + nt * 16 + lm;
        if (node >= N) continue;
        float r0 = acc[nt][0] + bv.x;
        float r1 = acc[nt][1] + bv.y;
        float r2 = acc[nt][2] + bv.z;
        float r3 = acc[nt][3] + bv.w;
        if (relu) {
            r0 = fmaxf(r0, 0.f); r1 = fmaxf(r1, 0.f);
            r2 = fmaxf(r2, 0.f); r3 = fmaxf(r3, 0.f);
        }
        if (outf) *(float4*)(outf + (long long)node * D + fb) = make_float4(r0, r1, r2, r3);
        if (outb) *(uint2*)(outb + (long long)node * 32 + (fb >> 1)) =
                      make_uint2(pack_bf(r0, r1), pack_bf(r2, r3));
    }
}

extern "C" void kernel_launch(void* const* d_in, const int* in_sizes, int n_in,
                              void* d_out, int out_size, void* d_ws, size_t ws_size,
                              hipStream_t stream) {
    const float* x   = (const float*)d_in[0];
    const int* ei    = (const int*)d_in[1];
    const float* W1l = (const float*)d_in[2];
    const float* W1r = (const float*)d_in[3];
    const float* b1  = (const float*)d_in[4];
    const float* W2l = (const float*)d_in[5];
    const float* W2r = (const float*)d_in[6];
    const float* b2  = (const float*)d_in[7];

    const int E = in_sizes[1] / 2;
    const int N = in_sizes[0] / D;     // requires N <= 131072 (17-bit packing)
    const int* src  = ei;
    const int* dstp = ei + E;
    const int NBK = (N + BNODES - 1) >> BSHIFT;   // 782 for N=100k
    const int G1 = 1024;
    const int CE = (E + G1 - 1) / G1;

    char* ws = (char*)d_ws;
    size_t off = 0;
    auto alloc = [&](size_t bytes) { void* p = ws + off; off = (off + bytes + 255) & ~(size_t)255; return p; };
    int* cnt2           = (int*)alloc((size_t)(NBK * 8) * 4);
    int* cur2           = (int*)alloc((size_t)(NBK * 8) * 4);
    int* bstart         = (int*)alloc((size_t)(NBK + 1) * 4);
    int* rowptr         = (int*)alloc((size_t)(N + 1) * 4);
    unsigned int* pairs = (unsigned int*)alloc((size_t)E * 4);
    int* csr            = (int*)alloc((size_t)E * 4);
    unsigned int* xb    = (unsigned int*)alloc((size_t)N * 32 * 4);  // bf16 x
    unsigned int* meanb = (unsigned int*)alloc((size_t)N * 32 * 4);  // bf16 mean
    unsigned int* hb    = (unsigned int*)alloc((size_t)N * 32 * 4);  // bf16 h

    float* out = (float*)d_out;

    // ---- cast features to bf16 ----
    cast_kernel<<<2048, 256, 0, stream>>>((const float4*)x, (uint2*)xb, N * 16);

    // ---- CSR build: bucket counting sort, dense writes ----
    zeroi_kernel<<<(NBK * 8 + 255) / 256, 256, 0, stream>>>(cnt2, NBK * 8);
    hist2_kernel<<<G1, 256, 0, stream>>>(dstp, cnt2, E, NBK, CE);
    scan2k_kernel<<<1, 256, 0, stream>>>(cnt2, cur2, bstart, NBK);
    binscatter_kernel<<<G1, 256, 0, stream>>>(src, dstp, cur2, pairs, E, NBK, CE);
    csr_build_kernel<<<NBK, 256, 0, stream>>>(pairs, bstart, rowptr, csr, N, NBK);

    const int linGrid = (N + 63) / 64;

    // ---- layer 1: gather bf16 x -> mean; MFMA linear emits bf16 h ----
    agg_bf_kernel<<<4096, 256, 0, stream>>>(xb, rowptr, csr, meanb, N);
    lin_mfma_kernel<<<linGrid, 256, 0, stream>>>(meanb, xb, W1l, W1r, b1, nullptr, hb, N, 1);

    // ---- layer 2: gather bf16 h -> mean; MFMA linear emits fp32 out ----
    agg_bf_kernel<<<4096, 256, 0, stream>>>(hb, rowptr, csr, meanb, N);
    lin_mfma_kernel<<<linGrid, 256, 0, stream>>>(meanb, hb, W2l, W2r, b2, out, nullptr, N, 0);
}

// Round 11
// 267.639 us; speedup vs baseline: 1.2152x; 1.2152x over previous
//
#include <hip/hip_runtime.h>

#define D 64
#define BSHIFT 9              // 512 nodes per bucket (runs of ~16 edges per (bucket,group))
#define BNODES (1 << BSHIFT)
#define NBK_MAX 512           // supports N up to 262144

typedef __attribute__((ext_vector_type(8))) short bf16x8;
typedef __attribute__((ext_vector_type(4))) float f32x4;

// ---------- bf16 helpers (bit-exact RNE pack, shift-based unpack) ----------
__device__ __forceinline__ unsigned int f2bf_rne(float f) {
    unsigned int b = __float_as_uint(f);
    return (b + 0x7fffu + ((b >> 16) & 1u)) >> 16;
}
__device__ __forceinline__ unsigned int pack_bf(float lo, float hi) {
    return f2bf_rne(lo) | (f2bf_rne(hi) << 16);
}
__device__ __forceinline__ float bflo(unsigned int u) { return __uint_as_float(u << 16); }
__device__ __forceinline__ float bfhi(unsigned int u) { return __uint_as_float(u & 0xffff0000u); }

// ---------- zero int region ----------
__global__ void zeroi_kernel(int* __restrict__ p, int n) {
    int i = blockIdx.x * blockDim.x + threadIdx.x;
    if (i < n) p[i] = 0;
}

// ---------- cast fp32 features -> packed bf16 (2 feats per uint) ----------
__global__ void cast_kernel(const float4* __restrict__ xin, uint2* __restrict__ xb, int n4) {
    int i = blockIdx.x * blockDim.x + threadIdx.x;
    int stride = gridDim.x * blockDim.x;
    for (; i < n4; i += stride) {
        float4 v = xin[i];
        uint2 o;
        o.x = pack_bf(v.x, v.y);
        o.y = pack_bf(v.z, v.w);
        xb[i] = o;
    }
}

// ---------- phase 1: per-(bucket,group) histogram. group = blockIdx&7 (~XCD) ----------
__global__ __launch_bounds__(256) void hist2_kernel(const int* __restrict__ dst,
                                                    int* __restrict__ cnt2,
                                                    int E, int NBK, int CE) {
    __shared__ int lh[NBK_MAX];
    for (int k = threadIdx.x; k < NBK; k += 256) lh[k] = 0;
    __syncthreads();
    int b = blockIdx.x, g = b & 7;
    int beg = b * CE, end = min(beg + CE, E);
    for (int e = beg + threadIdx.x; e < end; e += 256)
        atomicAdd(&lh[dst[e] >> BSHIFT], 1);
    __syncthreads();
    for (int k = threadIdx.x; k < NBK; k += 256)
        if (lh[k]) atomicAdd(&cnt2[(k << 3) | g], lh[k]);
}

// ---------- phase 2: exclusive scan of cnt2[NBK*8] -> cur2 + bstart (chunked) ----------
__global__ __launch_bounds__(256) void scan2k_kernel(const int* __restrict__ cnt2,
                                                     int* __restrict__ cur2,
                                                     int* __restrict__ bstart, int NBK) {
    __shared__ int s[256];
    int n = NBK << 3;
    int per = (n + 255) / 256;        // 7 at NBK=196
    int tid = threadIdx.x;
    int base = tid * per;
    int loc[32];
    int sum = 0;
    for (int j = 0; j < per; ++j) {
        int idx = base + j;
        int v = (idx < n) ? cnt2[idx] : 0;
        loc[j] = sum;                 // exclusive within thread
        sum += v;
    }
    s[tid] = sum;
    __syncthreads();
    for (int off = 1; off < 256; off <<= 1) {
        int t = (tid >= off) ? s[tid - off] : 0;
        __syncthreads();
        s[tid] += t;
        __syncthreads();
    }
    int ebase = s[tid] - sum;
    for (int j = 0; j < per; ++j) {
        int idx = base + j;
        if (idx < n) {
            int e = ebase + loc[j];
            cur2[idx] = e;
            if ((idx & 7) == 0) bstart[idx >> 3] = e;   // bucket start
        }
    }
    if (tid == 0) bstart[NBK] = s[255];  // == E
}

// ---------- phase 3: scatter packed (src | dst_low<<17) records ----------
__global__ __launch_bounds__(256) void binscatter_kernel(
    const int* __restrict__ src, const int* __restrict__ dst,
    int* __restrict__ cur2, unsigned int* __restrict__ pairs,
    int E, int NBK, int CE) {
    __shared__ int lh[NBK_MAX];
    __shared__ int lbase[NBK_MAX];
    for (int k = threadIdx.x; k < NBK; k += 256) lh[k] = 0;
    __syncthreads();
    int b = blockIdx.x, g = b & 7;
    int beg = b * CE, end = min(beg + CE, E);
    for (int e = beg + threadIdx.x; e < end; e += 256)
        atomicAdd(&lh[dst[e] >> BSHIFT], 1);
    __syncthreads();
    for (int k = threadIdx.x; k < NBK; k += 256) {
        int c = lh[k];
        if (c) lbase[k] = atomicAdd(&cur2[(k << 3) | g], c);
        lh[k] = 0;
    }
    __syncthreads();
    for (int e = beg + threadIdx.x; e < end; e += 256) {
        int d = dst[e];
        int k = d >> BSHIFT;
        int r = atomicAdd(&lh[k], 1);
        pairs[lbase[k] + r] = (unsigned int)src[e] | ((unsigned int)(d & (BNODES - 1)) << 17);
    }
}

// ---------- phase 4: one workgroup per bucket -> rowptr + dst-sorted csr ----------
__global__ __launch_bounds__(256) void csr_build_kernel(
    const unsigned int* __restrict__ pairs, const int* __restrict__ bstart,
    int* __restrict__ rowptr, int* __restrict__ csr, int N, int NBK) {
    __shared__ int lcnt[BNODES];
    __shared__ int lofs[BNODES];
    __shared__ int s[256];
    int k = blockIdx.x;
    int tid = threadIdx.x;
    int node0 = k << BSHIFT;
    int nnodes = min(BNODES, N - node0);
    int rbeg = bstart[k], rend = bstart[k + 1];

    for (int j = tid; j < BNODES; j += 256) lcnt[j] = 0;
    __syncthreads();
    for (int i = rbeg + tid; i < rend; i += 256)
        atomicAdd(&lcnt[pairs[i] >> 17], 1);
    __syncthreads();
    int v0 = lcnt[2 * tid], v1 = lcnt[2 * tid + 1];
    int ps = v0 + v1;
    s[tid] = ps;
    __syncthreads();
    for (int off = 1; off < 256; off <<= 1) {
        int t = (tid >= off) ? s[tid - off] : 0;
        __syncthreads();
        s[tid] += t;
        __syncthreads();
    }
    int ebase = s[tid] - ps;
    lofs[2 * tid] = ebase;
    lofs[2 * tid + 1] = ebase + v0;
    __syncthreads();
    for (int j = tid; j < nnodes; j += 256) {
        int p = rbeg + lofs[j];
        rowptr[node0 + j] = p;
        lcnt[j] = p;
    }
    if (k == NBK - 1 && tid == 0) rowptr[N] = rend;
    __syncthreads();
    for (int i = rbeg + tid; i < rend; i += 256) {
        unsigned int rec = pairs[i];
        int j = rec >> 17;
        int pos = atomicAdd(&lcnt[j], 1);
        csr[pos] = (int)(rec & 0x1FFFFu);
    }
}

// ---------- aggregation, bf16: 8 nodes per wave; 8 lanes x uint4 per row, 4-deep unroll ----------
// 32 independent row-loads in flight per wave; stores 1KB contiguous per wave.
__global__ __launch_bounds__(256) void agg_bf_kernel(
    const unsigned int* __restrict__ xb, const int* __restrict__ rowptr,
    const int* __restrict__ csr, unsigned int* __restrict__ meanb, int N) {
    int lane = threadIdx.x & 63;
    int q  = lane >> 3;         // which of the wave's 8 nodes
    int fl = lane & 7;          // uint4 segment index (uints 4fl..4fl+3)
    int wid = blockIdx.x * (blockDim.x >> 6) + (threadIdx.x >> 6);
    int nwaves = gridDim.x * (blockDim.x >> 6);
    int noct = (N + 7) >> 3;

    for (int p = wid; p < noct; p += nwaves) {
        int node = p * 8 + q;
        bool valid = node < N;
        int beg = 0, end = 0;
        if (valid) { beg = rowptr[node]; end = rowptr[node + 1]; }
        float s0 = 0.f, s1 = 0.f, s2 = 0.f, s3 = 0.f;
        float s4 = 0.f, s5 = 0.f, s6 = 0.f, s7 = 0.f;
        int j = beg;
        for (; j + 4 <= end; j += 4) {
            int i0 = csr[j], i1 = csr[j + 1], i2 = csr[j + 2], i3 = csr[j + 3];
            uint4 u0 = *(const uint4*)(xb + i0 * 32 + fl * 4);
            uint4 u1 = *(const uint4*)(xb + i1 * 32 + fl * 4);
            uint4 u2 = *(const uint4*)(xb + i2 * 32 + fl * 4);
            uint4 u3 = *(const uint4*)(xb + i3 * 32 + fl * 4);
            s0 += bflo(u0.x) + bflo(u1.x) + bflo(u2.x) + bflo(u3.x);
            s1 += bfhi(u0.x) + bfhi(u1.x) + bfhi(u2.x) + bfhi(u3.x);
            s2 += bflo(u0.y) + bflo(u1.y) + bflo(u2.y) + bflo(u3.y);
            s3 += bfhi(u0.y) + bfhi(u1.y) + bfhi(u2.y) + bfhi(u3.y);
            s4 += bflo(u0.z) + bflo(u1.z) + bflo(u2.z) + bflo(u3.z);
            s5 += bfhi(u0.z) + bfhi(u1.z) + bfhi(u2.z) + bfhi(u3.z);
            s6 += bflo(u0.w) + bflo(u1.w) + bflo(u2.w) + bflo(u3.w);
            s7 += bfhi(u0.w) + bfhi(u1.w) + bfhi(u2.w) + bfhi(u3.w);
        }
        for (; j < end; ++j) {
            uint4 u = *(const uint4*)(xb + csr[j] * 32 + fl * 4);
            s0 += bflo(u.x); s1 += bfhi(u.x);
            s2 += bflo(u.y); s3 += bfhi(u.y);
            s4 += bflo(u.z); s5 += bfhi(u.z);
            s6 += bflo(u.w); s7 += bfhi(u.w);
        }
        if (valid) {
            float inv = 1.0f / fmaxf((float)(end - beg), 1.0f);
            uint4 o;
            o.x = pack_bf(s0 * inv, s1 * inv);
            o.y = pack_bf(s2 * inv, s3 * inv);
            o.z = pack_bf(s4 * inv, s5 * inv);
            o.w = pack_bf(s6 * inv, s7 * inv);
            *(uint4*)(meanb + node * 32 + fl * 4) = o;
        }
    }
}

// ---------- linear via MFMA: out[f][node] tiles, D = W * A (no LDS) ----------
__global__ __launch_bounds__(256) void lin_mfma_kernel(
    const unsigned int* __restrict__ meanb, const unsigned int* __restrict__ xin,
    const float* __restrict__ Wl, const float* __restrict__ Wr,
    const float* __restrict__ bias,
    float* __restrict__ outf, unsigned int* __restrict__ outb, int N, int relu) {
    int tid = threadIdx.x;
    int ft   = tid >> 6;        // wave id = f-tile 0..3
    int lane = tid & 63;
    int lm   = lane & 15;
    int quad = lane >> 4;

    // hi/lo split weight frags for the 4 K-steps (W ~ bf16(W) + bf16(W - bf16(W)))
    int f_a = ft * 16 + lm;
    bf16x8 wh[4], wlo[4];
#pragma unroll
    for (int s = 0; s < 4; ++s) {
        int k8 = s * 32 + quad * 8;
        const float* Wsrc = (k8 < 64) ? Wl : Wr;
        const float* p = Wsrc + f_a * 64 + (k8 & 63);
        float4 w0 = *(const float4*)p;
        float4 w1 = *(const float4*)(p + 4);
        float w[8] = {w0.x, w0.y, w0.z, w0.w, w1.x, w1.y, w1.z, w1.w};
        bf16x8 h, l;
#pragma unroll
        for (int j = 0; j < 8; ++j) {
            unsigned int hb = f2bf_rne(w[j]);
            float hf = __uint_as_float(hb << 16);
            unsigned int lb = f2bf_rne(w[j] - hf);
            h[j] = (short)hb;
            l[j] = (short)lb;
        }
        wh[s] = h;
        wlo[s] = l;
    }

    int node0 = blockIdx.x * 64;
    f32x4 acc[4];
#pragma unroll
    for (int nt = 0; nt < 4; ++nt) acc[nt] = (f32x4){0.f, 0.f, 0.f, 0.f};

#pragma unroll
    for (int nt = 0; nt < 4; ++nt) {
        int node = node0 + nt * 16 + lm;
        bool v = node < N;
        const unsigned int* mrow = meanb + (long long)node * 32;
        const unsigned int* xrow = xin   + (long long)node * 32;
#pragma unroll
        for (int s = 0; s < 4; ++s) {
            uint4 u = make_uint4(0u, 0u, 0u, 0u);
            if (v) {
                const unsigned int* srcrow = (s < 2) ? mrow : xrow;
                u = *(const uint4*)(srcrow + (s & 1) * 16 + quad * 4);
            }
            union { uint4 u4; bf16x8 v8; } cv;
            cv.u4 = u;
            acc[nt] = __builtin_amdgcn_mfma_f32_16x16x32_bf16(wh[s],  cv.v8, acc[nt], 0, 0, 0);
            acc[nt] = __builtin_amdgcn_mfma_f32_16x16x32_bf16(wlo[s], cv.v8, acc[nt], 0, 0, 0);
        }
    }

    int fb = ft * 16 + quad * 4;
    float4 bv = *(const float4*)(bias + fb);
#pragma unroll
    for (int nt = 0; nt < 4; ++nt) {
        int node = node0 + nt * 16 + lm;
        if (node >= N) continue;
        float r0 = acc[nt][0] + bv.x;
        float r1 = acc[nt][1] + bv.y;
        float r2 = acc[nt][2] + bv.z;
        float r3 = acc[nt][3] + bv.w;
        if (relu) {
            r0 = fmaxf(r0, 0.f); r1 = fmaxf(r1, 0.f);
            r2 = fmaxf(r2, 0.f); r3 = fmaxf(r3, 0.f);
        }
        if (outf) *(float4*)(outf + (long long)node * D + fb) = make_float4(r0, r1, r2, r3);
        if (outb) *(uint2*)(outb + (long long)node * 32 + (fb >> 1)) =
                      make_uint2(pack_bf(r0, r1), pack_bf(r2, r3));
    }
}

extern "C" void kernel_launch(void* const* d_in, const int* in_sizes, int n_in,
                              void* d_out, int out_size, void* d_ws, size_t ws_size,
                              hipStream_t stream) {
    const float* x   = (const float*)d_in[0];
    const int* ei    = (const int*)d_in[1];
    const float* W1l = (const float*)d_in[2];
    const float* W1r = (const float*)d_in[3];
    const float* b1  = (const float*)d_in[4];
    const float* W2l = (const float*)d_in[5];
    const float* W2r = (const float*)d_in[6];
    const float* b2  = (const float*)d_in[7];

    const int E = in_sizes[1] / 2;
    const int N = in_sizes[0] / D;     // requires N <= 131072 (17-bit packing)
    const int* src  = ei;
    const int* dstp = ei + E;
    const int NBK = (N + BNODES - 1) >> BSHIFT;   // 196 for N=100k
    const int G1 = 512;                           // 16-edge runs per (bucket,group)
    const int CE = (E + G1 - 1) / G1;

    char* ws = (char*)d_ws;
    size_t off = 0;
    auto alloc = [&](size_t bytes) { void* p = ws + off; off = (off + bytes + 255) & ~(size_t)255; return p; };
    int* cnt2           = (int*)alloc((size_t)(NBK * 8) * 4);
    int* cur2           = (int*)alloc((size_t)(NBK * 8) * 4);
    int* bstart         = (int*)alloc((size_t)(NBK + 1) * 4);
    int* rowptr         = (int*)alloc((size_t)(N + 1) * 4);
    unsigned int* pairs = (unsigned int*)alloc((size_t)E * 4);
    int* csr            = (int*)alloc((size_t)E * 4);
    unsigned int* xb    = (unsigned int*)alloc((size_t)N * 32 * 4);  // bf16 x
    unsigned int* meanb = (unsigned int*)alloc((size_t)N * 32 * 4);  // bf16 mean
    unsigned int* hb    = (unsigned int*)alloc((size_t)N * 32 * 4);  // bf16 h

    float* out = (float*)d_out;

    // ---- cast features to bf16 ----
    cast_kernel<<<2048, 256, 0, stream>>>((const float4*)x, (uint2*)xb, N * 16);

    // ---- CSR build: bucket counting sort, dense writes ----
    zeroi_kernel<<<(NBK * 8 + 255) / 256, 256, 0, stream>>>(cnt2, NBK * 8);
    hist2_kernel<<<G1, 256, 0, stream>>>(dstp, cnt2, E, NBK, CE);
    scan2k_kernel<<<1, 256, 0, stream>>>(cnt2, cur2, bstart, NBK);
    binscatter_kernel<<<G1, 256, 0, stream>>>(src, dstp, cur2, pairs, E, NBK, CE);
    csr_build_kernel<<<NBK, 256, 0, stream>>>(pairs, bstart, rowptr, csr, N, NBK);

    const int linGrid = (N + 63) / 64;

    // ---- layer 1: gather bf16 x -> mean; MFMA linear emits bf16 h ----
    agg_bf_kernel<<<4096, 256, 0, stream>>>(xb, rowptr, csr, meanb, N);
    lin_mfma_kernel<<<linGrid, 256, 0, stream>>>(meanb, xb, W1l, W1r, b1, nullptr, hb, N, 1);

    // ---- layer 2: gather bf16 h -> mean; MFMA linear emits fp32 out ----
    agg_bf_kernel<<<4096, 256, 0, stream>>>(hb, rowptr, csr, meanb, N);
    lin_mfma_kernel<<<linGrid, 256, 0, stream>>>(meanb, hb, W2l, W2r, b2, out, nullptr, N, 0);
}